// Round 9
// baseline (399.167 us; speedup 1.0000x reference)
//
#include <hip/hip_runtime.h>

#define N_NODES 50000
#define N_EDGES 800000
#define BN_EPS 1e-5f

__device__ __forceinline__ void fma4(float4& a, float s, const float4& w) {
    a.x += s * w.x; a.y += s * w.y; a.z += s * w.z; a.w += s * w.w;
}
__device__ __forceinline__ void add4(float4& a, const float4& b) {
    a.x += b.x; a.y += b.y; a.z += b.z; a.w += b.w;
}

// ---------------------------------------------------------------------------
__global__ void zero_i(int* __restrict__ p, int n) {
    int i = blockIdx.x * blockDim.x + threadIdx.x;
    int stride = gridDim.x * blockDim.x;
    for (; i < n; i += stride) p[i] = 0;
}

// ---------------------------------------------------------------------------
// CSR build
__global__ void hist_kernel(const int* __restrict__ dst, int* __restrict__ cnt) {
    int i = blockIdx.x * blockDim.x + threadIdx.x;
    int stride = gridDim.x * blockDim.x;
    for (; i < N_EDGES; i += stride) atomicAdd(&cnt[dst[i]], 1);
}
__global__ void scan1_kernel(const int* __restrict__ cnt, int* __restrict__ rp,
                             int* __restrict__ bsum) {
    __shared__ int s[256];
    int t = threadIdx.x;
    int idx = blockIdx.x * 256 + t;
    int v = (idx < N_NODES) ? cnt[idx] : 0;
    s[t] = v;
    __syncthreads();
    for (int off = 1; off < 256; off <<= 1) {
        int x = 0;
        if (t >= off) x = s[t - off];
        __syncthreads();
        s[t] += x;
        __syncthreads();
    }
    if (idx < N_NODES) rp[idx] = s[t] - v;
    if (t == 255) bsum[blockIdx.x] = s[255];
}
__global__ void scan2_kernel(int* __restrict__ bsum, int nb, float* __restrict__ stats) {
    __shared__ int s[256];
    int t = threadIdx.x;
    for (int i = t; i < 5 * 256; i += 256) stats[i] = 0.f;
    int v = (t < nb) ? bsum[t] : 0;
    s[t] = v;
    __syncthreads();
    for (int off = 1; off < 256; off <<= 1) {
        int x = 0;
        if (t >= off) x = s[t - off];
        __syncthreads();
        s[t] += x;
        __syncthreads();
    }
    if (t < nb) bsum[t] = s[t] - v;
}
__global__ void scan3_kernel(int* __restrict__ rp, const int* __restrict__ bsum,
                             int* __restrict__ cnt) {
    int idx = blockIdx.x * 256 + threadIdx.x;
    if (idx < N_NODES) {
        rp[idx] += bsum[blockIdx.x];
        cnt[idx] = 0;
    }
    if (idx == 0) rp[N_NODES] = N_EDGES;
}
__global__ void fill_kernel(const int* __restrict__ src, const int* __restrict__ dst,
                            const int* __restrict__ rp, int* __restrict__ cur,
                            int* __restrict__ ssrc) {
    int i = blockIdx.x * blockDim.x + threadIdx.x;
    int stride = gridDim.x * blockDim.x;
    for (; i < N_EDGES; i += stride) {
        int d = dst[i];
        int p = rp[d] + atomicAdd(&cur[d], 1);
        ssrc[p] = src[i];
    }
}

// ---------------------------------------------------------------------------
// embedding Linear(5,32)+ReLU with fused BN stats
__global__ __launch_bounds__(256) void emb_fused(
    const float* __restrict__ x, const float* __restrict__ W,
    const float* __restrict__ b, float* __restrict__ out,
    float* __restrict__ stats) {
    __shared__ float lsum[32], lssq[32];
    if (threadIdx.x < 32) { lsum[threadIdx.x] = 0.f; lssq[threadIdx.x] = 0.f; }
    __syncthreads();
    const int o = threadIdx.x & 31;
    const int total = N_NODES * 32;
    float mys = 0.f, myq = 0.f;
    for (int base = blockIdx.x * 256; base < total; base += gridDim.x * 256) {
        int idx = base + threadIdx.x;
        float acc = 0.f;
        if (idx < total) {
            int n = idx >> 5;
            const float* xr = x + n * 5;
            acc = b[o];
#pragma unroll
            for (int k = 0; k < 5; ++k) acc += xr[k] * W[k * 32 + o];
            acc = fmaxf(acc, 0.f);
            out[idx] = acc;
        }
        mys += acc;
        myq += acc * acc;
    }
    mys += __shfl_xor(mys, 32);
    myq += __shfl_xor(myq, 32);
    if ((threadIdx.x & 63) < 32) { atomicAdd(&lsum[o], mys); atomicAdd(&lssq[o], myq); }
    __syncthreads();
    if (threadIdx.x < 32) {
        atomicAdd(&stats[threadIdx.x], lsum[threadIdx.x]);
        atomicAdd(&stats[32 + threadIdx.x], lssq[threadIdx.x]);
    }
}

// ---------------------------------------------------------------------------
// in-place batchnorm (+ optional relu), float4
__global__ __launch_bounds__(256) void bn_apply(
    float4* __restrict__ h, const float* __restrict__ g,
    const float* __restrict__ beta, const float* __restrict__ stats,
    int logD, int relu) {
    const int D = 1 << logD;
    const int total4 = N_NODES << (logD - 2);
    const float invN = 1.f / (float)N_NODES;
    int idx = blockIdx.x * blockDim.x + threadIdx.x;
    int stride = gridDim.x * blockDim.x;
    for (; idx < total4; idx += stride) {
        int f = (idx & ((D >> 2) - 1)) << 2;
        float4 v = h[idx];
        float* vp = (float*)&v;
#pragma unroll
        for (int c = 0; c < 4; ++c) {
            float m = stats[f + c] * invN;
            float var = stats[D + f + c] * invN - m * m;
            float y = (vp[c] - m) * rsqrtf(var + BN_EPS) * g[f + c] + beta[f + c];
            if (relu) y = fmaxf(y, 0.f);
            vp[c] = y;
        }
        h[idx] = v;
    }
}

// ---------------------------------------------------------------------------
// agg[n][4q..4q+3] = sum over CSR row of h[ssrc[e]][4q..4q+3]; 4-way edge unroll
template <int LOGD>
__global__ __launch_bounds__(256) void gather_agg(
    const float* __restrict__ h, const int* __restrict__ rp,
    const int* __restrict__ ssrc, float4* __restrict__ agg) {
    constexpr int QSH = LOGD - 2;
    int tid = blockIdx.x * 256 + threadIdx.x;
    int node = tid >> QSH;
    if (node >= N_NODES) return;
    int q = tid & ((1 << QSH) - 1);
    int e0 = rp[node], e1 = rp[node + 1];
    float4 acc = make_float4(0.f, 0.f, 0.f, 0.f);
    int e = e0;
    for (; e + 4 <= e1; e += 4) {
        int s0 = ssrc[e], s1 = ssrc[e + 1], s2 = ssrc[e + 2], s3 = ssrc[e + 3];
        float4 v0 = ((const float4*)(h + ((size_t)s0 << LOGD)))[q];
        float4 v1 = ((const float4*)(h + ((size_t)s1 << LOGD)))[q];
        float4 v2 = ((const float4*)(h + ((size_t)s2 << LOGD)))[q];
        float4 v3 = ((const float4*)(h + ((size_t)s3 << LOGD)))[q];
        add4(v0, v1); add4(v2, v3); add4(acc, v0); add4(acc, v2);
    }
    for (; e < e1; ++e) {
        float4 v = ((const float4*)(h + ((size_t)ssrc[e] << LOGD)))[q];
        add4(acc, v);
    }
    agg[tid] = acc;
}

// ---------------------------------------------------------------------------
// dual matmul: weights in LDS, software-pipelined node-row loads (A/B double
// buffer, statically named), fused output BN stats.
// out[n][o] = brel[o] + agg[n]@Wrel[:,o] + h[n]@Wroot[:,o]
template <int DIN, int DOUT, int OBL>
__global__ __launch_bounds__(256) void gconv_lds(
    const float* __restrict__ h, const float* __restrict__ agg,
    const float* __restrict__ Wrel, const float* __restrict__ brel,
    const float* __restrict__ Wroot, float* __restrict__ out,
    float* __restrict__ stats_out) {
    constexpr int LPN = OBL / 4;
    constexpr int SLOTS = 256 / LPN;
    constexpr int NPT = 4;
    constexpr int KS = 8;
    constexpr int NS = DIN / KS;  // even (4 or 8)
    constexpr int TOT4 = DIN * OBL / 4;
    __shared__ __align__(16) float wl[2 * DIN * OBL];
    __shared__ float lsum[OBL], lssq[OBL];
    const int ob0 = blockIdx.y * OBL;
    for (int e4 = threadIdx.x; e4 < TOT4; e4 += 256) {
        int k = e4 / (OBL / 4);
        int j = (e4 % (OBL / 4)) * 4;
        ((float4*)wl)[e4] = *(const float4*)(Wrel + (size_t)k * DOUT + ob0 + j);
        ((float4*)wl)[TOT4 + e4] = *(const float4*)(Wroot + (size_t)k * DOUT + ob0 + j);
    }
    if (threadIdx.x < OBL) { lsum[threadIdx.x] = 0.f; lssq[threadIdx.x] = 0.f; }
    __syncthreads();

    const int q = threadIdx.x & (LPN - 1);
    const int slot = threadIdx.x / LPN;
    const int o0 = ob0 + q * 4;
    const int nbase = blockIdx.x * (SLOTS * NPT) + slot;

    const float4* hrow[NPT];
    const float4* arow[NPT];
#pragma unroll
    for (int i = 0; i < NPT; ++i) {
        int n = nbase + i * SLOTS;
        int nn = (n < N_NODES) ? n : 0;
        hrow[i] = (const float4*)(h + (size_t)nn * DIN);
        arow[i] = (const float4*)(agg + (size_t)nn * DIN);
    }

    float4 bias = *(const float4*)(brel + o0);
    float4 acc[NPT];
#pragma unroll
    for (int i = 0; i < NPT; ++i) acc[i] = bias;

    float4 hvA[NPT][2], avA[NPT][2], hvB[NPT][2], avB[NPT][2];

#define LOADG(BH, BA, S)                                \
    _Pragma("unroll") for (int i = 0; i < NPT; ++i) {   \
        BH[i][0] = hrow[i][(S) * 2];                    \
        BH[i][1] = hrow[i][(S) * 2 + 1];                \
        BA[i][0] = arow[i][(S) * 2];                    \
        BA[i][1] = arow[i][(S) * 2 + 1];                \
    }
#define FMAS(BH, BA, S)                                                        \
    _Pragma("unroll") for (int kk = 0; kk < KS; ++kk) {                        \
        float4 wr = *(const float4*)&wl[((S) * KS + kk) * OBL + q * 4];        \
        float4 wo = *(const float4*)&wl[DIN * OBL + ((S) * KS + kk) * OBL + q * 4]; \
        _Pragma("unroll") for (int i = 0; i < NPT; ++i) {                      \
            fma4(acc[i], ((const float*)BA[i])[kk], wr);                       \
            fma4(acc[i], ((const float*)BH[i])[kk], wo);                       \
        }                                                                      \
    }

    LOADG(hvA, avA, 0);
#pragma unroll 1
    for (int s = 0; s < NS; s += 2) {
        LOADG(hvB, avB, s + 1);
        FMAS(hvA, avA, s);
        if (s + 2 < NS) LOADG(hvA, avA, s + 2);
        FMAS(hvB, avB, s + 1);
    }
#undef LOADG
#undef FMAS

#pragma unroll
    for (int i = 0; i < NPT; ++i) {
        int n = nbase + i * SLOTS;
        if (n < N_NODES)
            *(float4*)(out + (size_t)n * DOUT + o0) = acc[i];
        else
            acc[i] = make_float4(0.f, 0.f, 0.f, 0.f);
    }
    // fused BN stats over this kernel's output
    float4 s4 = make_float4(0.f, 0.f, 0.f, 0.f);
    float4 q4 = make_float4(0.f, 0.f, 0.f, 0.f);
#pragma unroll
    for (int i = 0; i < NPT; ++i) {
        s4.x += acc[i].x; s4.y += acc[i].y; s4.z += acc[i].z; s4.w += acc[i].w;
        q4.x += acc[i].x * acc[i].x; q4.y += acc[i].y * acc[i].y;
        q4.z += acc[i].z * acc[i].z; q4.w += acc[i].w * acc[i].w;
    }
#pragma unroll
    for (int d = LPN; d < 64; d <<= 1) {
        s4.x += __shfl_xor(s4.x, d); s4.y += __shfl_xor(s4.y, d);
        s4.z += __shfl_xor(s4.z, d); s4.w += __shfl_xor(s4.w, d);
        q4.x += __shfl_xor(q4.x, d); q4.y += __shfl_xor(q4.y, d);
        q4.z += __shfl_xor(q4.z, d); q4.w += __shfl_xor(q4.w, d);
    }
    if ((threadIdx.x & 63) < LPN) {
        int c = q * 4;
        atomicAdd(&lsum[c + 0], s4.x); atomicAdd(&lsum[c + 1], s4.y);
        atomicAdd(&lsum[c + 2], s4.z); atomicAdd(&lsum[c + 3], s4.w);
        atomicAdd(&lssq[c + 0], q4.x); atomicAdd(&lssq[c + 1], q4.y);
        atomicAdd(&lssq[c + 2], q4.z); atomicAdd(&lssq[c + 3], q4.w);
    }
    __syncthreads();
    if (threadIdx.x < OBL) {
        atomicAdd(&stats_out[ob0 + threadIdx.x], lsum[threadIdx.x]);
        atomicAdd(&stats_out[DOUT + ob0 + threadIdx.x], lssq[threadIdx.x]);
    }
}

// ---------------------------------------------------------------------------
// P = h@Wrel ; Q = h@Wroot + brel  (weights in LDS, pipelined node loads)
template <int DIN, int DOUT, int OBL>
__global__ __launch_bounds__(256) void prem_lds(
    const float* __restrict__ h, const float* __restrict__ Wrel,
    const float* __restrict__ brel, const float* __restrict__ Wroot,
    float* __restrict__ P, float* __restrict__ Q) {
    constexpr int LPN = OBL / 4;
    constexpr int SLOTS = 256 / LPN;
    constexpr int NPT = 4;
    constexpr int KS = 8;
    constexpr int NS = DIN / KS;
    constexpr int TOT4 = DIN * OBL / 4;
    __shared__ __align__(16) float wl[2 * DIN * OBL];
    const int ob0 = blockIdx.y * OBL;
    for (int e4 = threadIdx.x; e4 < TOT4; e4 += 256) {
        int k = e4 / (OBL / 4);
        int j = (e4 % (OBL / 4)) * 4;
        ((float4*)wl)[e4] = *(const float4*)(Wrel + (size_t)k * DOUT + ob0 + j);
        ((float4*)wl)[TOT4 + e4] = *(const float4*)(Wroot + (size_t)k * DOUT + ob0 + j);
    }
    __syncthreads();

    const int q = threadIdx.x & (LPN - 1);
    const int slot = threadIdx.x / LPN;
    const int o0 = ob0 + q * 4;
    const int nbase = blockIdx.x * (SLOTS * NPT) + slot;

    const float4* hrow[NPT];
#pragma unroll
    for (int i = 0; i < NPT; ++i) {
        int n = nbase + i * SLOTS;
        int nn = (n < N_NODES) ? n : 0;
        hrow[i] = (const float4*)(h + (size_t)nn * DIN);
    }

    float4 bias = *(const float4*)(brel + o0);
    float4 accp[NPT], accq[NPT];
#pragma unroll
    for (int i = 0; i < NPT; ++i) {
        accp[i] = make_float4(0.f, 0.f, 0.f, 0.f);
        accq[i] = bias;
    }

    float4 hvA[NPT][2], hvB[NPT][2];

#define LOADH(BH, S)                                    \
    _Pragma("unroll") for (int i = 0; i < NPT; ++i) {   \
        BH[i][0] = hrow[i][(S) * 2];                    \
        BH[i][1] = hrow[i][(S) * 2 + 1];                \
    }
#define FMASP(BH, S)                                                           \
    _Pragma("unroll") for (int kk = 0; kk < KS; ++kk) {                        \
        float4 wr = *(const float4*)&wl[((S) * KS + kk) * OBL + q * 4];        \
        float4 wo = *(const float4*)&wl[DIN * OBL + ((S) * KS + kk) * OBL + q * 4]; \
        _Pragma("unroll") for (int i = 0; i < NPT; ++i) {                      \
            float hh = ((const float*)BH[i])[kk];                              \
            fma4(accp[i], hh, wr);                                             \
            fma4(accq[i], hh, wo);                                             \
        }                                                                      \
    }

    LOADH(hvA, 0);
#pragma unroll 1
    for (int s = 0; s < NS; s += 2) {
        LOADH(hvB, s + 1);
        FMASP(hvA, s);
        if (s + 2 < NS) LOADH(hvA, s + 2);
        FMASP(hvB, s + 1);
    }
#undef LOADH
#undef FMASP

#pragma unroll
    for (int i = 0; i < NPT; ++i) {
        int n = nbase + i * SLOTS;
        if (n < N_NODES) {
            *(float4*)(P + (size_t)n * DOUT + o0) = accp[i];
            *(float4*)(Q + (size_t)n * DOUT + o0) = accq[i];
        }
    }
}

// ---------------------------------------------------------------------------
// out[n][f] = Q_preloaded + sum over CSR row of P[ssrc[e]][f]; fused BN stats.
template <int LOGD>
__global__ __launch_bounds__(256) void gather_add_fused(
    const float* __restrict__ P, const int* __restrict__ rp,
    const int* __restrict__ ssrc, float4* __restrict__ out,
    float* __restrict__ stats) {
    constexpr int D = 1 << LOGD;
    constexpr int Q4 = D / 4;
    __shared__ float lsum[D], lssq[D];
    if (threadIdx.x < D) { lsum[threadIdx.x] = 0.f; lssq[threadIdx.x] = 0.f; }
    __syncthreads();

    const int total = N_NODES * Q4;
    const int q = threadIdx.x & (Q4 - 1);
    float4 mys = make_float4(0.f, 0.f, 0.f, 0.f);
    float4 myq = make_float4(0.f, 0.f, 0.f, 0.f);

    for (int base = blockIdx.x * 256; base < total; base += gridDim.x * 256) {
        int tid = base + threadIdx.x;
        float4 acc = make_float4(0.f, 0.f, 0.f, 0.f);
        if (tid < total) {
            int node = tid >> (LOGD - 2);
            int e0 = rp[node], e1 = rp[node + 1];
            acc = out[tid];
            int e = e0;
            for (; e + 4 <= e1; e += 4) {
                int s0 = ssrc[e], s1 = ssrc[e + 1], s2 = ssrc[e + 2], s3 = ssrc[e + 3];
                float4 v0 = ((const float4*)(P + ((size_t)s0 << LOGD)))[q];
                float4 v1 = ((const float4*)(P + ((size_t)s1 << LOGD)))[q];
                float4 v2 = ((const float4*)(P + ((size_t)s2 << LOGD)))[q];
                float4 v3 = ((const float4*)(P + ((size_t)s3 << LOGD)))[q];
                add4(v0, v1); add4(v2, v3); add4(acc, v0); add4(acc, v2);
            }
            for (; e < e1; ++e) {
                float4 v = ((const float4*)(P + ((size_t)ssrc[e] << LOGD)))[q];
                add4(acc, v);
            }
            out[tid] = acc;
        }
        mys.x += acc.x; mys.y += acc.y; mys.z += acc.z; mys.w += acc.w;
        myq.x += acc.x * acc.x; myq.y += acc.y * acc.y;
        myq.z += acc.z * acc.z; myq.w += acc.w * acc.w;
    }
#pragma unroll
    for (int d = Q4; d < 64; d <<= 1) {
        mys.x += __shfl_xor(mys.x, d); mys.y += __shfl_xor(mys.y, d);
        mys.z += __shfl_xor(mys.z, d); mys.w += __shfl_xor(mys.w, d);
        myq.x += __shfl_xor(myq.x, d); myq.y += __shfl_xor(myq.y, d);
        myq.z += __shfl_xor(myq.z, d); myq.w += __shfl_xor(myq.w, d);
    }
    if ((threadIdx.x & 63) < Q4) {
        atomicAdd(&lsum[4 * q + 0], mys.x); atomicAdd(&lsum[4 * q + 1], mys.y);
        atomicAdd(&lsum[4 * q + 2], mys.z); atomicAdd(&lsum[4 * q + 3], mys.w);
        atomicAdd(&lssq[4 * q + 0], myq.x); atomicAdd(&lssq[4 * q + 1], myq.y);
        atomicAdd(&lssq[4 * q + 2], myq.z); atomicAdd(&lssq[4 * q + 3], myq.w);
    }
    __syncthreads();
    if (threadIdx.x < D) {
        atomicAdd(&stats[threadIdx.x], lsum[threadIdx.x]);
        atomicAdd(&stats[D + threadIdx.x], lssq[threadIdx.x]);
    }
}

// ---------------------------------------------------------------------------
// fused: BN(layer3)+ReLU -> Linear(32,16)+ReLU -> Linear(16,2)
__global__ __launch_bounds__(256) void outmlp_kernel(
    const float* __restrict__ h, const float* __restrict__ stats,
    const float* __restrict__ g, const float* __restrict__ beta,
    const float* __restrict__ W1, const float* __restrict__ b1,
    const float* __restrict__ W2, const float* __restrict__ b2,
    float* __restrict__ out) {
    int n = blockIdx.x * 256 + threadIdx.x;
    if (n >= N_NODES) return;
    const float invN = 1.f / (float)N_NODES;
    const float4* hr4 = (const float4*)(h + (size_t)n * 32);
    float hv[32];
#pragma unroll
    for (int k4 = 0; k4 < 8; ++k4) {
        float4 v = hr4[k4];
        float* vp = (float*)&v;
#pragma unroll
        for (int c = 0; c < 4; ++c) {
            int f = 4 * k4 + c;
            float m = stats[f] * invN;
            float var = stats[32 + f] * invN - m * m;
            hv[f] = fmaxf((vp[c] - m) * rsqrtf(var + BN_EPS) * g[f] + beta[f], 0.f);
        }
    }
    float hid[16];
#pragma unroll
    for (int j = 0; j < 16; ++j) hid[j] = b1[j];
#pragma unroll
    for (int k = 0; k < 32; ++k) {
        float hk = hv[k];
#pragma unroll
        for (int j = 0; j < 16; ++j) hid[j] += hk * W1[k * 16 + j];
    }
    float o0 = b2[0], o1 = b2[1];
#pragma unroll
    for (int j = 0; j < 16; ++j) {
        float t = fmaxf(hid[j], 0.f);
        o0 += t * W2[j * 2 + 0];
        o1 += t * W2[j * 2 + 1];
    }
    out[n * 2 + 0] = o0;
    out[n * 2 + 1] = o1;
}

// ---------------------------------------------------------------------------
extern "C" void kernel_launch(void* const* d_in, const int* in_sizes, int n_in,
                              void* d_out, int out_size, void* d_ws, size_t ws_size,
                              hipStream_t stream) {
    const float* x        = (const float*)d_in[0];
    const int*   ei       = (const int*)d_in[1];
    const int*   src      = ei;
    const int*   dst      = ei + N_EDGES;
    const float* emb_W    = (const float*)d_in[2];
    const float* emb_b    = (const float*)d_in[3];
    const float* emb_g    = (const float*)d_in[4];
    const float* emb_beta = (const float*)d_in[5];
    const float* out_W1   = (const float*)d_in[26];
    const float* out_b1   = (const float*)d_in[27];
    const float* out_W2   = (const float*)d_in[28];
    const float* out_b2   = (const float*)d_in[29];

    float* ws = (float*)d_ws;
    const size_t HMAX = (size_t)N_NODES * 128;
    float* hA    = ws;
    float* hB    = ws + HMAX;
    float* P     = ws + 2 * HMAX;                        // N x 64 max
    float* stats = ws + 2 * HMAX + (size_t)N_NODES * 64; // 5 x 256
    int*   rp    = (int*)(stats + 5 * 256);
    int*   cnt   = rp + N_NODES + 1;
    int*   bsum  = cnt + N_NODES;
    int*   ssrc  = bsum + 256;

    float* st0 = stats;        // emb BN (D=32)
    float* st1 = stats + 256;  // L0 (D=64)
    float* st2 = stats + 512;  // L1 (D=128)
    float* st3 = stats + 768;  // L2 (D=64)
    float* st4 = stats + 1024; // L3 (D=32)

    const int BS = 256;
    const int NB = (N_NODES + BS - 1) / BS;  // 196

    // ---- CSR build (stats zeroing folded into scan2, cnt re-zero into scan3) ----
    zero_i<<<64, BS, 0, stream>>>(cnt, N_NODES);
    hist_kernel<<<1024, BS, 0, stream>>>(dst, cnt);
    scan1_kernel<<<NB, 256, 0, stream>>>(cnt, rp, bsum);
    scan2_kernel<<<1, 256, 0, stream>>>(bsum, NB, stats);
    scan3_kernel<<<NB, 256, 0, stream>>>(rp, bsum, cnt);
    fill_kernel<<<1024, BS, 0, stream>>>(src, dst, rp, cnt, ssrc);

    // ---- embedding: Linear(5,32)+ReLU with fused stats; then BN in-place ----
    emb_fused<<<512, BS, 0, stream>>>(x, emb_W, emb_b, hA, st0);
    bn_apply<<<1563, BS, 0, stream>>>((float4*)hA, emb_g, emb_beta, st0, 5, 0);

    // ---- layer 0: 32 -> 64  (OBL=32) ----
    gather_agg<5><<<(N_NODES * 8 + BS - 1) / BS, BS, 0, stream>>>(hA, rp, ssrc, (float4*)P);
    gconv_lds<32, 64, 32><<<dim3((N_NODES + 127) / 128, 2), BS, 0, stream>>>(
        hA, P, (const float*)d_in[6], (const float*)d_in[7], (const float*)d_in[8], hB, st1);
    bn_apply<<<2048, BS, 0, stream>>>((float4*)hB, (const float*)d_in[9], (const float*)d_in[10], st1, 6, 1);

    // ---- layer 1: 64 -> 128  (OBL=32) ----
    gather_agg<6><<<(N_NODES * 16 + BS - 1) / BS, BS, 0, stream>>>(hB, rp, ssrc, (float4*)P);
    gconv_lds<64, 128, 32><<<dim3((N_NODES + 127) / 128, 4), BS, 0, stream>>>(
        hB, P, (const float*)d_in[11], (const float*)d_in[12], (const float*)d_in[13], hA, st2);
    bn_apply<<<2048, BS, 0, stream>>>((float4*)hA, (const float*)d_in[14], (const float*)d_in[15], st2, 7, 1);

    // ---- layer 2: 128 -> 64  (OBL=16) ----
    prem_lds<128, 64, 16><<<dim3((N_NODES + 255) / 256, 4), BS, 0, stream>>>(
        hA, (const float*)d_in[16], (const float*)d_in[17], (const float*)d_in[18], P, hB);
    gather_add_fused<6><<<512, BS, 0, stream>>>(P, rp, ssrc, (float4*)hB, st3);
    bn_apply<<<2048, BS, 0, stream>>>((float4*)hB, (const float*)d_in[19], (const float*)d_in[20], st3, 6, 1);

    // ---- layer 3: 64 -> 32  (OBL=16) ----
    prem_lds<64, 32, 16><<<dim3((N_NODES + 255) / 256, 2), BS, 0, stream>>>(
        hB, (const float*)d_in[21], (const float*)d_in[22], (const float*)d_in[23], P, hA);
    gather_add_fused<5><<<512, BS, 0, stream>>>(P, rp, ssrc, (float4*)hA, st4);

    // ---- fused BN(L3)+ReLU + output MLP ----
    outmlp_kernel<<<NB, BS, 0, stream>>>(
        hA, st4, (const float*)d_in[24], (const float*)d_in[25],
        out_W1, out_b1, out_W2, out_b2, (float*)d_out);
}

// Round 10
// 377.579 us; speedup vs baseline: 1.0572x; 1.0572x over previous
//
#include <hip/hip_runtime.h>

#define N_NODES 50000
#define N_EDGES 800000
#define BN_EPS 1e-5f

__device__ __forceinline__ void fma4(float4& a, float s, const float4& w) {
    a.x += s * w.x; a.y += s * w.y; a.z += s * w.z; a.w += s * w.w;
}
__device__ __forceinline__ void add4(float4& a, const float4& b) {
    a.x += b.x; a.y += b.y; a.z += b.z; a.w += b.w;
}

// ---------------------------------------------------------------------------
__global__ void zero_i(int* __restrict__ p, int n) {
    int i = blockIdx.x * blockDim.x + threadIdx.x;
    int stride = gridDim.x * blockDim.x;
    for (; i < n; i += stride) p[i] = 0;
}

// ---------------------------------------------------------------------------
// CSR build
__global__ void hist_kernel(const int* __restrict__ dst, int* __restrict__ cnt) {
    int i = blockIdx.x * blockDim.x + threadIdx.x;
    int stride = gridDim.x * blockDim.x;
    for (; i < N_EDGES; i += stride) atomicAdd(&cnt[dst[i]], 1);
}
__global__ void scan1_kernel(const int* __restrict__ cnt, int* __restrict__ rp,
                             int* __restrict__ bsum) {
    __shared__ int s[256];
    int t = threadIdx.x;
    int idx = blockIdx.x * 256 + t;
    int v = (idx < N_NODES) ? cnt[idx] : 0;
    s[t] = v;
    __syncthreads();
    for (int off = 1; off < 256; off <<= 1) {
        int x = 0;
        if (t >= off) x = s[t - off];
        __syncthreads();
        s[t] += x;
        __syncthreads();
    }
    if (idx < N_NODES) rp[idx] = s[t] - v;
    if (t == 255) bsum[blockIdx.x] = s[255];
}
__global__ void scan2_kernel(int* __restrict__ bsum, int nb, float* __restrict__ stats) {
    __shared__ int s[256];
    int t = threadIdx.x;
    for (int i = t; i < 5 * 256; i += 256) stats[i] = 0.f;
    int v = (t < nb) ? bsum[t] : 0;
    s[t] = v;
    __syncthreads();
    for (int off = 1; off < 256; off <<= 1) {
        int x = 0;
        if (t >= off) x = s[t - off];
        __syncthreads();
        s[t] += x;
        __syncthreads();
    }
    if (t < nb) bsum[t] = s[t] - v;
}
__global__ void scan3_kernel(int* __restrict__ rp, const int* __restrict__ bsum,
                             int* __restrict__ cnt) {
    int idx = blockIdx.x * 256 + threadIdx.x;
    if (idx < N_NODES) {
        rp[idx] += bsum[blockIdx.x];
        cnt[idx] = 0;
    }
    if (idx == 0) rp[N_NODES] = N_EDGES;
}
// after fill completes, cnt[n] == degree(n) again (cursor fully incremented)
__global__ void fill_kernel(const int* __restrict__ src, const int* __restrict__ dst,
                            const int* __restrict__ rp, int* __restrict__ cur,
                            int* __restrict__ ssrc) {
    int i = blockIdx.x * blockDim.x + threadIdx.x;
    int stride = gridDim.x * blockDim.x;
    for (; i < N_EDGES; i += stride) {
        int d = dst[i];
        int p = rp[d] + atomicAdd(&cur[d], 1);
        ssrc[p] = src[i];
    }
}

// ---------------------------------------------------------------------------
// embedding Linear(5,32)+ReLU with fused BN stats (BN applied later, folded)
__global__ __launch_bounds__(256) void emb_fused(
    const float* __restrict__ x, const float* __restrict__ W,
    const float* __restrict__ b, float* __restrict__ out,
    float* __restrict__ stats) {
    __shared__ float lsum[32], lssq[32];
    if (threadIdx.x < 32) { lsum[threadIdx.x] = 0.f; lssq[threadIdx.x] = 0.f; }
    __syncthreads();
    const int o = threadIdx.x & 31;
    const int total = N_NODES * 32;
    float mys = 0.f, myq = 0.f;
    for (int base = blockIdx.x * 256; base < total; base += gridDim.x * 256) {
        int idx = base + threadIdx.x;
        float acc = 0.f;
        if (idx < total) {
            int n = idx >> 5;
            const float* xr = x + n * 5;
            acc = b[o];
#pragma unroll
            for (int k = 0; k < 5; ++k) acc += xr[k] * W[k * 32 + o];
            acc = fmaxf(acc, 0.f);
            out[idx] = acc;
        }
        mys += acc;
        myq += acc * acc;
    }
    mys += __shfl_xor(mys, 32);
    myq += __shfl_xor(myq, 32);
    if ((threadIdx.x & 63) < 32) { atomicAdd(&lsum[o], mys); atomicAdd(&lssq[o], myq); }
    __syncthreads();
    if (threadIdx.x < 32) {
        atomicAdd(&stats[threadIdx.x], lsum[threadIdx.x]);
        atomicAdd(&stats[32 + threadIdx.x], lssq[threadIdx.x]);
    }
}

// ---------------------------------------------------------------------------
// compute per-feature BN scale/shift into LDS from raw stats (sync at end)
template <int D>
__device__ __forceinline__ void bn_finalize_lds(
    const float* __restrict__ stats, const float* __restrict__ g,
    const float* __restrict__ beta, float* sc, float* sh) {
    const float invN = 1.f / (float)N_NODES;
    for (int f = threadIdx.x; f < D; f += 256) {
        float m = stats[f] * invN;
        float var = stats[D + f] * invN - m * m;
        float a = g[f] * rsqrtf(var + BN_EPS);
        sc[f] = a;
        sh[f] = beta[f] - m * a;
    }
    __syncthreads();
}

// ---------------------------------------------------------------------------
// in-place batchnorm (+ optional relu), float4  (only used after layer 0)
__global__ __launch_bounds__(256) void bn_apply(
    float4* __restrict__ h, const float* __restrict__ g,
    const float* __restrict__ beta, const float* __restrict__ stats,
    int logD, int relu) {
    const int D = 1 << logD;
    const int total4 = N_NODES << (logD - 2);
    const float invN = 1.f / (float)N_NODES;
    int idx = blockIdx.x * blockDim.x + threadIdx.x;
    int stride = gridDim.x * blockDim.x;
    for (; idx < total4; idx += stride) {
        int f = (idx & ((D >> 2) - 1)) << 2;
        float4 v = h[idx];
        float* vp = (float*)&v;
#pragma unroll
        for (int c = 0; c < 4; ++c) {
            float m = stats[f + c] * invN;
            float var = stats[D + f + c] * invN - m * m;
            float y = (vp[c] - m) * rsqrtf(var + BN_EPS) * g[f + c] + beta[f + c];
            if (relu) y = fmaxf(y, 0.f);
            vp[c] = y;
        }
        h[idx] = v;
    }
}

// ---------------------------------------------------------------------------
// agg[n][4q..4q+3] = sum over CSR row of h[ssrc[e]][4q..4q+3]; 4-way edge unroll
template <int LOGD>
__global__ __launch_bounds__(256) void gather_agg(
    const float* __restrict__ h, const int* __restrict__ rp,
    const int* __restrict__ ssrc, float4* __restrict__ agg) {
    constexpr int QSH = LOGD - 2;
    int tid = blockIdx.x * 256 + threadIdx.x;
    int node = tid >> QSH;
    if (node >= N_NODES) return;
    int q = tid & ((1 << QSH) - 1);
    int e0 = rp[node], e1 = rp[node + 1];
    float4 acc = make_float4(0.f, 0.f, 0.f, 0.f);
    int e = e0;
    for (; e + 4 <= e1; e += 4) {
        int s0 = ssrc[e], s1 = ssrc[e + 1], s2 = ssrc[e + 2], s3 = ssrc[e + 3];
        float4 v0 = ((const float4*)(h + ((size_t)s0 << LOGD)))[q];
        float4 v1 = ((const float4*)(h + ((size_t)s1 << LOGD)))[q];
        float4 v2 = ((const float4*)(h + ((size_t)s2 << LOGD)))[q];
        float4 v3 = ((const float4*)(h + ((size_t)s3 << LOGD)))[q];
        add4(v0, v1); add4(v2, v3); add4(acc, v0); add4(acc, v2);
    }
    for (; e < e1; ++e) {
        float4 v = ((const float4*)(h + ((size_t)ssrc[e] << LOGD)))[q];
        add4(acc, v);
    }
    agg[tid] = acc;
}

// ---------------------------------------------------------------------------
// Layer-0 dual matmul: inputs are RAW (pre-BN) emb outputs; the input BN is
// applied per-node via linearity: bn(agg) = a*agg + deg*b, bn(h) = a*h + b.
// Weights in LDS; fused output BN stats. (r8-proven loop structure)
template <int DIN, int DOUT, int OBL>
__global__ __launch_bounds__(256) void gconv_bn0(
    const float* __restrict__ h, const float* __restrict__ agg,
    const float* __restrict__ Wrel, const float* __restrict__ brel,
    const float* __restrict__ Wroot, float* __restrict__ out,
    const float* __restrict__ stats_in, const float* __restrict__ g_in,
    const float* __restrict__ beta_in, const int* __restrict__ deg,
    float* __restrict__ stats_out) {
    constexpr int LPN = OBL / 4;
    constexpr int SLOTS = 256 / LPN;
    constexpr int NPT = 4;
    constexpr int KS = 8;
    constexpr int TOT4 = DIN * OBL / 4;
    __shared__ __align__(16) float wl[2 * DIN * OBL];
    __shared__ __align__(16) float sc[DIN];
    __shared__ __align__(16) float sh[DIN];
    __shared__ float lsum[OBL], lssq[OBL];
    const int ob0 = blockIdx.y * OBL;
    for (int e4 = threadIdx.x; e4 < TOT4; e4 += 256) {
        int k = e4 / (OBL / 4);
        int j = (e4 % (OBL / 4)) * 4;
        ((float4*)wl)[e4] = *(const float4*)(Wrel + (size_t)k * DOUT + ob0 + j);
        ((float4*)wl)[TOT4 + e4] = *(const float4*)(Wroot + (size_t)k * DOUT + ob0 + j);
    }
    if (threadIdx.x < OBL) { lsum[threadIdx.x] = 0.f; lssq[threadIdx.x] = 0.f; }
    bn_finalize_lds<DIN>(stats_in, g_in, beta_in, sc, sh);  // syncs

    const int q = threadIdx.x & (LPN - 1);
    const int slot = threadIdx.x / LPN;
    const int o0 = ob0 + q * 4;
    const int nbase = blockIdx.x * (SLOTS * NPT) + slot;

    float degf[NPT];
#pragma unroll
    for (int i = 0; i < NPT; ++i) {
        int n = nbase + i * SLOTS;
        degf[i] = (n < N_NODES) ? (float)deg[n] : 0.f;
    }

    float4 bias = *(const float4*)(brel + o0);
    float4 acc[NPT];
#pragma unroll
    for (int i = 0; i < NPT; ++i) acc[i] = bias;

#pragma unroll 1
    for (int s = 0; s < DIN / KS; ++s) {
        const int k0 = s * KS;
        float4 s2[2] = {((const float4*)sc)[k0 / 4], ((const float4*)sc)[k0 / 4 + 1]};
        float4 t2[2] = {((const float4*)sh)[k0 / 4], ((const float4*)sh)[k0 / 4 + 1]};
        const float* scp = (const float*)s2;
        const float* shp = (const float*)t2;
        float4 hv[NPT][2], av[NPT][2];
#pragma unroll
        for (int i = 0; i < NPT; ++i) {
            int n = nbase + i * SLOTS;
            int nn = (n < N_NODES) ? n : 0;
            const float4* hr = (const float4*)(h + (size_t)nn * DIN + k0);
            const float4* ar = (const float4*)(agg + (size_t)nn * DIN + k0);
            hv[i][0] = hr[0]; hv[i][1] = hr[1];
            av[i][0] = ar[0]; av[i][1] = ar[1];
        }
#pragma unroll
        for (int kk = 0; kk < KS; ++kk) {
            float4 wr = *(const float4*)&wl[(k0 + kk) * OBL + q * 4];
            float4 wo = *(const float4*)&wl[DIN * OBL + (k0 + kk) * OBL + q * 4];
#pragma unroll
            for (int i = 0; i < NPT; ++i) {
                float a  = fmaf(((const float*)av[i])[kk], scp[kk], degf[i] * shp[kk]);
                float hh = fmaf(((const float*)hv[i])[kk], scp[kk], shp[kk]);
                fma4(acc[i], a, wr);
                fma4(acc[i], hh, wo);
            }
        }
    }
#pragma unroll
    for (int i = 0; i < NPT; ++i) {
        int n = nbase + i * SLOTS;
        if (n < N_NODES)
            *(float4*)(out + (size_t)n * DOUT + o0) = acc[i];
        else
            acc[i] = make_float4(0.f, 0.f, 0.f, 0.f);
    }
    float4 s4 = make_float4(0.f, 0.f, 0.f, 0.f);
    float4 q4 = make_float4(0.f, 0.f, 0.f, 0.f);
#pragma unroll
    for (int i = 0; i < NPT; ++i) {
        s4.x += acc[i].x; s4.y += acc[i].y; s4.z += acc[i].z; s4.w += acc[i].w;
        q4.x += acc[i].x * acc[i].x; q4.y += acc[i].y * acc[i].y;
        q4.z += acc[i].z * acc[i].z; q4.w += acc[i].w * acc[i].w;
    }
#pragma unroll
    for (int d = LPN; d < 64; d <<= 1) {
        s4.x += __shfl_xor(s4.x, d); s4.y += __shfl_xor(s4.y, d);
        s4.z += __shfl_xor(s4.z, d); s4.w += __shfl_xor(s4.w, d);
        q4.x += __shfl_xor(q4.x, d); q4.y += __shfl_xor(q4.y, d);
        q4.z += __shfl_xor(q4.z, d); q4.w += __shfl_xor(q4.w, d);
    }
    if ((threadIdx.x & 63) < LPN) {
        int c = q * 4;
        atomicAdd(&lsum[c + 0], s4.x); atomicAdd(&lsum[c + 1], s4.y);
        atomicAdd(&lsum[c + 2], s4.z); atomicAdd(&lsum[c + 3], s4.w);
        atomicAdd(&lssq[c + 0], q4.x); atomicAdd(&lssq[c + 1], q4.y);
        atomicAdd(&lssq[c + 2], q4.z); atomicAdd(&lssq[c + 3], q4.w);
    }
    __syncthreads();
    if (threadIdx.x < OBL) {
        atomicAdd(&stats_out[ob0 + threadIdx.x], lsum[threadIdx.x]);
        atomicAdd(&stats_out[DOUT + ob0 + threadIdx.x], lssq[threadIdx.x]);
    }
}

// ---------------------------------------------------------------------------
// dual matmul, inputs already normalized (r8-proven), fused output BN stats.
template <int DIN, int DOUT, int OBL>
__global__ __launch_bounds__(256) void gconv_lds(
    const float* __restrict__ h, const float* __restrict__ agg,
    const float* __restrict__ Wrel, const float* __restrict__ brel,
    const float* __restrict__ Wroot, float* __restrict__ out,
    float* __restrict__ stats_out) {
    constexpr int LPN = OBL / 4;
    constexpr int SLOTS = 256 / LPN;
    constexpr int NPT = 4;
    constexpr int KS = 8;
    constexpr int TOT4 = DIN * OBL / 4;
    __shared__ __align__(16) float wl[2 * DIN * OBL];
    __shared__ float lsum[OBL], lssq[OBL];
    const int ob0 = blockIdx.y * OBL;
    for (int e4 = threadIdx.x; e4 < TOT4; e4 += 256) {
        int k = e4 / (OBL / 4);
        int j = (e4 % (OBL / 4)) * 4;
        ((float4*)wl)[e4] = *(const float4*)(Wrel + (size_t)k * DOUT + ob0 + j);
        ((float4*)wl)[TOT4 + e4] = *(const float4*)(Wroot + (size_t)k * DOUT + ob0 + j);
    }
    if (threadIdx.x < OBL) { lsum[threadIdx.x] = 0.f; lssq[threadIdx.x] = 0.f; }
    __syncthreads();

    const int q = threadIdx.x & (LPN - 1);
    const int slot = threadIdx.x / LPN;
    const int o0 = ob0 + q * 4;
    const int nbase = blockIdx.x * (SLOTS * NPT) + slot;

    float4 bias = *(const float4*)(brel + o0);
    float4 acc[NPT];
#pragma unroll
    for (int i = 0; i < NPT; ++i) acc[i] = bias;

#pragma unroll 1
    for (int s = 0; s < DIN / KS; ++s) {
        const int k0 = s * KS;
        float4 hv[NPT][2], av[NPT][2];
#pragma unroll
        for (int i = 0; i < NPT; ++i) {
            int n = nbase + i * SLOTS;
            int nn = (n < N_NODES) ? n : 0;
            const float4* hr = (const float4*)(h + (size_t)nn * DIN + k0);
            const float4* ar = (const float4*)(agg + (size_t)nn * DIN + k0);
            hv[i][0] = hr[0]; hv[i][1] = hr[1];
            av[i][0] = ar[0]; av[i][1] = ar[1];
        }
#pragma unroll
        for (int kk = 0; kk < KS; ++kk) {
            float4 wr = *(const float4*)&wl[(k0 + kk) * OBL + q * 4];
            float4 wo = *(const float4*)&wl[DIN * OBL + (k0 + kk) * OBL + q * 4];
#pragma unroll
            for (int i = 0; i < NPT; ++i) {
                fma4(acc[i], ((const float*)av[i])[kk], wr);
                fma4(acc[i], ((const float*)hv[i])[kk], wo);
            }
        }
    }
#pragma unroll
    for (int i = 0; i < NPT; ++i) {
        int n = nbase + i * SLOTS;
        if (n < N_NODES)
            *(float4*)(out + (size_t)n * DOUT + o0) = acc[i];
        else
            acc[i] = make_float4(0.f, 0.f, 0.f, 0.f);
    }
    float4 s4 = make_float4(0.f, 0.f, 0.f, 0.f);
    float4 q4 = make_float4(0.f, 0.f, 0.f, 0.f);
#pragma unroll
    for (int i = 0; i < NPT; ++i) {
        s4.x += acc[i].x; s4.y += acc[i].y; s4.z += acc[i].z; s4.w += acc[i].w;
        q4.x += acc[i].x * acc[i].x; q4.y += acc[i].y * acc[i].y;
        q4.z += acc[i].z * acc[i].z; q4.w += acc[i].w * acc[i].w;
    }
#pragma unroll
    for (int d = LPN; d < 64; d <<= 1) {
        s4.x += __shfl_xor(s4.x, d); s4.y += __shfl_xor(s4.y, d);
        s4.z += __shfl_xor(s4.z, d); s4.w += __shfl_xor(s4.w, d);
        q4.x += __shfl_xor(q4.x, d); q4.y += __shfl_xor(q4.y, d);
        q4.z += __shfl_xor(q4.z, d); q4.w += __shfl_xor(q4.w, d);
    }
    if ((threadIdx.x & 63) < LPN) {
        int c = q * 4;
        atomicAdd(&lsum[c + 0], s4.x); atomicAdd(&lsum[c + 1], s4.y);
        atomicAdd(&lsum[c + 2], s4.z); atomicAdd(&lsum[c + 3], s4.w);
        atomicAdd(&lssq[c + 0], q4.x); atomicAdd(&lssq[c + 1], q4.y);
        atomicAdd(&lssq[c + 2], q4.z); atomicAdd(&lssq[c + 3], q4.w);
    }
    __syncthreads();
    if (threadIdx.x < OBL) {
        atomicAdd(&stats_out[ob0 + threadIdx.x], lsum[threadIdx.x]);
        atomicAdd(&stats_out[DOUT + ob0 + threadIdx.x], lssq[threadIdx.x]);
    }
}

// ---------------------------------------------------------------------------
// P = bnrelu(h)@Wrel ; Q = bnrelu(h)@Wroot + brel — input BN+ReLU folded
// per-node on the row reads (r8 loop structure + fold).
template <int DIN, int DOUT, int OBL>
__global__ __launch_bounds__(256) void prem_bn(
    const float* __restrict__ h, const float* __restrict__ Wrel,
    const float* __restrict__ brel, const float* __restrict__ Wroot,
    float* __restrict__ P, float* __restrict__ Q,
    const float* __restrict__ stats_in, const float* __restrict__ g_in,
    const float* __restrict__ beta_in) {
    constexpr int LPN = OBL / 4;
    constexpr int SLOTS = 256 / LPN;
    constexpr int NPT = 4;
    constexpr int KS = 8;
    constexpr int TOT4 = DIN * OBL / 4;
    __shared__ __align__(16) float wl[2 * DIN * OBL];
    __shared__ __align__(16) float sc[DIN];
    __shared__ __align__(16) float sh[DIN];
    const int ob0 = blockIdx.y * OBL;
    for (int e4 = threadIdx.x; e4 < TOT4; e4 += 256) {
        int k = e4 / (OBL / 4);
        int j = (e4 % (OBL / 4)) * 4;
        ((float4*)wl)[e4] = *(const float4*)(Wrel + (size_t)k * DOUT + ob0 + j);
        ((float4*)wl)[TOT4 + e4] = *(const float4*)(Wroot + (size_t)k * DOUT + ob0 + j);
    }
    bn_finalize_lds<DIN>(stats_in, g_in, beta_in, sc, sh);  // syncs

    const int q = threadIdx.x & (LPN - 1);
    const int slot = threadIdx.x / LPN;
    const int o0 = ob0 + q * 4;
    const int nbase = blockIdx.x * (SLOTS * NPT) + slot;

    float4 bias = *(const float4*)(brel + o0);
    float4 accp[NPT], accq[NPT];
#pragma unroll
    for (int i = 0; i < NPT; ++i) {
        accp[i] = make_float4(0.f, 0.f, 0.f, 0.f);
        accq[i] = bias;
    }

#pragma unroll 1
    for (int s = 0; s < DIN / KS; ++s) {
        const int k0 = s * KS;
        float4 s2[2] = {((const float4*)sc)[k0 / 4], ((const float4*)sc)[k0 / 4 + 1]};
        float4 t2[2] = {((const float4*)sh)[k0 / 4], ((const float4*)sh)[k0 / 4 + 1]};
        const float* scp = (const float*)s2;
        const float* shp = (const float*)t2;
        float4 hv[NPT][2];
#pragma unroll
        for (int i = 0; i < NPT; ++i) {
            int n = nbase + i * SLOTS;
            int nn = (n < N_NODES) ? n : 0;
            const float4* hr = (const float4*)(h + (size_t)nn * DIN + k0);
            hv[i][0] = hr[0]; hv[i][1] = hr[1];
        }
#pragma unroll
        for (int kk = 0; kk < KS; ++kk) {
            float4 wr = *(const float4*)&wl[(k0 + kk) * OBL + q * 4];
            float4 wo = *(const float4*)&wl[DIN * OBL + (k0 + kk) * OBL + q * 4];
#pragma unroll
            for (int i = 0; i < NPT; ++i) {
                float hh = fmaxf(fmaf(((const float*)hv[i])[kk], scp[kk], shp[kk]), 0.f);
                fma4(accp[i], hh, wr);
                fma4(accq[i], hh, wo);
            }
        }
    }
#pragma unroll
    for (int i = 0; i < NPT; ++i) {
        int n = nbase + i * SLOTS;
        if (n < N_NODES) {
            *(float4*)(P + (size_t)n * DOUT + o0) = accp[i];
            *(float4*)(Q + (size_t)n * DOUT + o0) = accq[i];
        }
    }
}

// ---------------------------------------------------------------------------
// out[n][f] = Q_preloaded + sum over CSR row of P[ssrc[e]][f]; fused BN stats.
template <int LOGD>
__global__ __launch_bounds__(256) void gather_add_fused(
    const float* __restrict__ P, const int* __restrict__ rp,
    const int* __restrict__ ssrc, float4* __restrict__ out,
    float* __restrict__ stats) {
    constexpr int D = 1 << LOGD;
    constexpr int Q4 = D / 4;
    __shared__ float lsum[D], lssq[D];
    if (threadIdx.x < D) { lsum[threadIdx.x] = 0.f; lssq[threadIdx.x] = 0.f; }
    __syncthreads();

    const int total = N_NODES * Q4;
    const int q = threadIdx.x & (Q4 - 1);
    float4 mys = make_float4(0.f, 0.f, 0.f, 0.f);
    float4 myq = make_float4(0.f, 0.f, 0.f, 0.f);

    for (int base = blockIdx.x * 256; base < total; base += gridDim.x * 256) {
        int tid = base + threadIdx.x;
        float4 acc = make_float4(0.f, 0.f, 0.f, 0.f);
        if (tid < total) {
            int node = tid >> (LOGD - 2);
            int e0 = rp[node], e1 = rp[node + 1];
            acc = out[tid];
            int e = e0;
            for (; e + 4 <= e1; e += 4) {
                int s0 = ssrc[e], s1 = ssrc[e + 1], s2 = ssrc[e + 2], s3 = ssrc[e + 3];
                float4 v0 = ((const float4*)(P + ((size_t)s0 << LOGD)))[q];
                float4 v1 = ((const float4*)(P + ((size_t)s1 << LOGD)))[q];
                float4 v2 = ((const float4*)(P + ((size_t)s2 << LOGD)))[q];
                float4 v3 = ((const float4*)(P + ((size_t)s3 << LOGD)))[q];
                add4(v0, v1); add4(v2, v3); add4(acc, v0); add4(acc, v2);
            }
            for (; e < e1; ++e) {
                float4 v = ((const float4*)(P + ((size_t)ssrc[e] << LOGD)))[q];
                add4(acc, v);
            }
            out[tid] = acc;
        }
        mys.x += acc.x; mys.y += acc.y; mys.z += acc.z; mys.w += acc.w;
        myq.x += acc.x * acc.x; myq.y += acc.y * acc.y;
        myq.z += acc.z * acc.z; myq.w += acc.w * acc.w;
    }
#pragma unroll
    for (int d = Q4; d < 64; d <<= 1) {
        mys.x += __shfl_xor(mys.x, d); mys.y += __shfl_xor(mys.y, d);
        mys.z += __shfl_xor(mys.z, d); mys.w += __shfl_xor(mys.w, d);
        myq.x += __shfl_xor(myq.x, d); myq.y += __shfl_xor(myq.y, d);
        myq.z += __shfl_xor(myq.z, d); myq.w += __shfl_xor(myq.w, d);
    }
    if ((threadIdx.x & 63) < Q4) {
        atomicAdd(&lsum[4 * q + 0], mys.x); atomicAdd(&lsum[4 * q + 1], mys.y);
        atomicAdd(&lsum[4 * q + 2], mys.z); atomicAdd(&lsum[4 * q + 3], mys.w);
        atomicAdd(&lssq[4 * q + 0], myq.x); atomicAdd(&lssq[4 * q + 1], myq.y);
        atomicAdd(&lssq[4 * q + 2], myq.z); atomicAdd(&lssq[4 * q + 3], myq.w);
    }
    __syncthreads();
    if (threadIdx.x < D) {
        atomicAdd(&stats[threadIdx.x], lsum[threadIdx.x]);
        atomicAdd(&stats[D + threadIdx.x], lssq[threadIdx.x]);
    }
}

// ---------------------------------------------------------------------------
// fused: BN(layer3)+ReLU -> Linear(32,16)+ReLU -> Linear(16,2)
__global__ __launch_bounds__(256) void outmlp_kernel(
    const float* __restrict__ h, const float* __restrict__ stats,
    const float* __restrict__ g, const float* __restrict__ beta,
    const float* __restrict__ W1, const float* __restrict__ b1,
    const float* __restrict__ W2, const float* __restrict__ b2,
    float* __restrict__ out) {
    int n = blockIdx.x * 256 + threadIdx.x;
    if (n >= N_NODES) return;
    const float invN = 1.f / (float)N_NODES;
    const float4* hr4 = (const float4*)(h + (size_t)n * 32);
    float hv[32];
#pragma unroll
    for (int k4 = 0; k4 < 8; ++k4) {
        float4 v = hr4[k4];
        float* vp = (float*)&v;
#pragma unroll
        for (int c = 0; c < 4; ++c) {
            int f = 4 * k4 + c;
            float m = stats[f] * invN;
            float var = stats[32 + f] * invN - m * m;
            hv[f] = fmaxf((vp[c] - m) * rsqrtf(var + BN_EPS) * g[f] + beta[f], 0.f);
        }
    }
    float hid[16];
#pragma unroll
    for (int j = 0; j < 16; ++j) hid[j] = b1[j];
#pragma unroll
    for (int k = 0; k < 32; ++k) {
        float hk = hv[k];
#pragma unroll
        for (int j = 0; j < 16; ++j) hid[j] += hk * W1[k * 16 + j];
    }
    float o0 = b2[0], o1 = b2[1];
#pragma unroll
    for (int j = 0; j < 16; ++j) {
        float t = fmaxf(hid[j], 0.f);
        o0 += t * W2[j * 2 + 0];
        o1 += t * W2[j * 2 + 1];
    }
    out[n * 2 + 0] = o0;
    out[n * 2 + 1] = o1;
}

// ---------------------------------------------------------------------------
extern "C" void kernel_launch(void* const* d_in, const int* in_sizes, int n_in,
                              void* d_out, int out_size, void* d_ws, size_t ws_size,
                              hipStream_t stream) {
    const float* x        = (const float*)d_in[0];
    const int*   ei       = (const int*)d_in[1];
    const int*   src      = ei;
    const int*   dst      = ei + N_EDGES;
    const float* emb_W    = (const float*)d_in[2];
    const float* emb_b    = (const float*)d_in[3];
    const float* emb_g    = (const float*)d_in[4];
    const float* emb_beta = (const float*)d_in[5];
    const float* out_W1   = (const float*)d_in[26];
    const float* out_b1   = (const float*)d_in[27];
    const float* out_W2   = (const float*)d_in[28];
    const float* out_b2   = (const float*)d_in[29];

    float* ws = (float*)d_ws;
    const size_t HMAX = (size_t)N_NODES * 128;
    float* hA    = ws;
    float* hB    = ws + HMAX;
    float* P     = ws + 2 * HMAX;                        // N x 64 max
    float* stats = ws + 2 * HMAX + (size_t)N_NODES * 64; // 5 x 256
    int*   rp    = (int*)(stats + 5 * 256);
    int*   cnt   = rp + N_NODES + 1;
    int*   bsum  = cnt + N_NODES;
    int*   ssrc  = bsum + 256;

    float* st0 = stats;        // emb BN (D=32)
    float* st1 = stats + 256;  // L0 (D=64)
    float* st2 = stats + 512;  // L1 (D=128)
    float* st3 = stats + 768;  // L2 (D=64)
    float* st4 = stats + 1024; // L3 (D=32)

    const int BS = 256;
    const int NB = (N_NODES + BS - 1) / BS;  // 196

    // ---- CSR build ----
    zero_i<<<64, BS, 0, stream>>>(cnt, N_NODES);
    hist_kernel<<<1024, BS, 0, stream>>>(dst, cnt);
    scan1_kernel<<<NB, 256, 0, stream>>>(cnt, rp, bsum);
    scan2_kernel<<<1, 256, 0, stream>>>(bsum, NB, stats);
    scan3_kernel<<<NB, 256, 0, stream>>>(rp, bsum, cnt);
    fill_kernel<<<1024, BS, 0, stream>>>(src, dst, rp, cnt, ssrc);
    // after fill: cnt[n] == degree(n)

    // ---- embedding: Linear(5,32)+ReLU with fused stats (BN deferred/folded) ----
    emb_fused<<<512, BS, 0, stream>>>(x, emb_W, emb_b, hA, st0);

    // ---- layer 0: 32 -> 64 — gather RAW emb output; BN folded per-node ----
    gather_agg<5><<<(N_NODES * 8 + BS - 1) / BS, BS, 0, stream>>>(hA, rp, ssrc, (float4*)P);
    gconv_bn0<32, 64, 32><<<dim3((N_NODES + 127) / 128, 2), BS, 0, stream>>>(
        hA, P, (const float*)d_in[6], (const float*)d_in[7], (const float*)d_in[8], hB,
        st0, emb_g, emb_beta, cnt, st1);
    // L0 output feeds a per-edge gather next -> must materialize BN+ReLU
    bn_apply<<<2048, BS, 0, stream>>>((float4*)hB, (const float*)d_in[9], (const float*)d_in[10], st1, 6, 1);

    // ---- layer 1: 64 -> 128 ----
    gather_agg<6><<<(N_NODES * 16 + BS - 1) / BS, BS, 0, stream>>>(hB, rp, ssrc, (float4*)P);
    gconv_lds<64, 128, 32><<<dim3((N_NODES + 127) / 128, 4), BS, 0, stream>>>(
        hB, P, (const float*)d_in[11], (const float*)d_in[12], (const float*)d_in[13], hA, st2);

    // ---- layer 2: 128 -> 64 — BN(st2)+ReLU folded per-node into prem ----
    prem_bn<128, 64, 16><<<dim3((N_NODES + 255) / 256, 4), BS, 0, stream>>>(
        hA, (const float*)d_in[16], (const float*)d_in[17], (const float*)d_in[18], P, hB,
        st2, (const float*)d_in[14], (const float*)d_in[15]);
    gather_add_fused<6><<<512, BS, 0, stream>>>(P, rp, ssrc, (float4*)hB, st3);

    // ---- layer 3: 64 -> 32 — BN(st3)+ReLU folded per-node into prem ----
    prem_bn<64, 32, 16><<<dim3((N_NODES + 255) / 256, 2), BS, 0, stream>>>(
        hB, (const float*)d_in[21], (const float*)d_in[22], (const float*)d_in[23], P, hA,
        st3, (const float*)d_in[19], (const float*)d_in[20]);
    gather_add_fused<5><<<512, BS, 0, stream>>>(P, rp, ssrc, (float4*)hA, st4);

    // ---- fused BN(L3)+ReLU + output MLP ----
    outmlp_kernel<<<NB, BS, 0, stream>>>(
        hA, st4, (const float*)d_in[24], (const float*)d_in[25],
        out_W1, out_b1, out_W2, out_b2, (float*)d_out);
}